// Round 2
// baseline (812.843 us; speedup 1.0000x reference)
//
#include <hip/hip_runtime.h>
#include <hip/hip_bf16.h>

#define N_NODES 100000
#define N_EDGES 3200000
#define D 256
#define SCAN_CH 2048                                  // elems per scan block
#define NBLK_S ((N_NODES + 1 + SCAN_CH - 1) / SCAN_CH)  // 49 scan blocks

typedef __attribute__((ext_vector_type(8))) short short8;   // 8 bf16 (4 VGPRs)
typedef __attribute__((ext_vector_type(4))) float floatx4;  // MFMA C/D

__device__ __forceinline__ unsigned short f32_to_bf16_rne(float f) {
    unsigned int u = __float_as_uint(f);
    u += 0x7FFFu + ((u >> 16) & 1u);
    return (unsigned short)(u >> 16);
}
__device__ __forceinline__ float bf16_bits_to_f32(unsigned short b) {
    return __uint_as_float(((unsigned int)b) << 16);
}
__device__ __forceinline__ float blo(unsigned int x) { return __uint_as_float(x << 16); }
__device__ __forceinline__ float bhi(unsigned int x) { return __uint_as_float(x & 0xFFFF0000u); }

// ---------------- W (fp32 [K][N]) -> bf16 MFMA-B-fragment order --------------
__global__ __launch_bounds__(256) void convert_w_k(const float* __restrict__ w,
                                                   unsigned short* __restrict__ wsw) {
    int t = blockIdx.x * 256 + threadIdx.x;
    int j     = t & 7;
    int lane  = (t >> 3) & 63;
    int kstep = (t >> 9) & 7;
    int ntile = t >> 12;
    int k = kstep * 32 + (lane >> 4) * 8 + j;
    int n = ntile * 16 + (lane & 15);
    wsw[t] = f32_to_bf16_rne(w[k * D + n]);
}

// ---------------- xw = x @ W (bf16 MFMA), output bf16 ------------------------
// 512 threads / 8 waves per block: 128 rows/block, 782 blocks.
__global__ __launch_bounds__(512) void gemm_xw_k(const float* __restrict__ x,
                                                 const unsigned short* __restrict__ wsw,
                                                 unsigned short* __restrict__ xwb) {
    __shared__ uint4 wlds[8192];  // 128 KiB swizzled bf16 W
    const int tid = threadIdx.x;
#pragma unroll
    for (int i = 0; i < 16; ++i) {
        int idx = i * 512 + tid;
        wlds[idx] = ((const uint4*)wsw)[idx];
    }
    __syncthreads();

    const int lane = tid & 63;
    const int wave = tid >> 6;            // 0..7
    const int q    = lane >> 4;
    const int ml   = lane & 15;
    const long rowBase = (long)blockIdx.x * 128 + wave * 16;
    long arow = rowBase + ml;
    if (arow >= N_NODES) arow = 0;
    const float* xr = x + arow * (long)D;

    floatx4 acc[16];
#pragma unroll
    for (int i = 0; i < 16; ++i) acc[i] = (floatx4){0.f, 0.f, 0.f, 0.f};

    const short8* wfrag = (const short8*)wlds;

#pragma unroll
    for (int ks = 0; ks < 8; ++ks) {
        const float4 a0 = *(const float4*)(xr + ks * 32 + q * 8);
        const float4 a1 = *(const float4*)(xr + ks * 32 + q * 8 + 4);
        short8 af;
        af[0] = (short)f32_to_bf16_rne(a0.x);
        af[1] = (short)f32_to_bf16_rne(a0.y);
        af[2] = (short)f32_to_bf16_rne(a0.z);
        af[3] = (short)f32_to_bf16_rne(a0.w);
        af[4] = (short)f32_to_bf16_rne(a1.x);
        af[5] = (short)f32_to_bf16_rne(a1.y);
        af[6] = (short)f32_to_bf16_rne(a1.z);
        af[7] = (short)f32_to_bf16_rne(a1.w);
#pragma unroll
        for (int nt = 0; nt < 16; ++nt) {
            acc[nt] = __builtin_amdgcn_mfma_f32_16x16x32_bf16(
                af, wfrag[(nt * 8 + ks) * 64 + lane], acc[nt], 0, 0, 0);
        }
    }

#pragma unroll
    for (int nt = 0; nt < 16; ++nt) {
#pragma unroll
        for (int r = 0; r < 4; ++r) {
            long orow = rowBase + q * 4 + r;
            if (orow < N_NODES)
                xwb[orow * (long)D + nt * 16 + ml] = f32_to_bf16_rne(acc[nt][r]);
        }
    }
}

// ---------------- direct per-row histogram (global atomics, L2-resident) -----
__global__ __launch_bounds__(256) void rhist_k(const int* __restrict__ erow,
                                               int* __restrict__ rcnt) {
    int i = blockIdx.x * 256 + threadIdx.x;
    const int stride = gridDim.x * 256;
    for (; i < N_EDGES; i += stride) atomicAdd(&rcnt[erow[i]], 1);
}

// ---------------- scan stage A: block-local exclusive scan + block sums ------
// 1024 threads, 2 elems/thread (2048/block). Wave-shuffle scan: 2 barriers.
__global__ __launch_bounds__(1024) void scanA_k(const int* __restrict__ rcnt,
                                                int* __restrict__ offsets,
                                                int* __restrict__ bsums) {
    const int t = threadIdx.x;
    const int g = blockIdx.x * SCAN_CH + 2 * t;
    int v0 = (g     < N_NODES + 1) ? rcnt[g]     : 0;
    int v1 = (g + 1 < N_NODES + 1) ? rcnt[g + 1] : 0;
    int s = v0 + v1;

    const int lane = t & 63;
    const int wv   = t >> 6;          // 0..15
    int x = s;
#pragma unroll
    for (int d = 1; d < 64; d <<= 1) {
        int u = __shfl_up(x, d);
        if (lane >= d) x += u;
    }
    __shared__ int wsum[16];
    if (lane == 63) wsum[wv] = x;
    __syncthreads();
    if (wv == 0) {
        int y = (lane < 16) ? wsum[lane] : 0;
#pragma unroll
        for (int d = 1; d < 16; d <<= 1) {
            int u = __shfl_up(y, d);
            if (lane >= d) y += u;
        }
        if (lane < 16) wsum[lane] = y;
    }
    __syncthreads();
    int waveoff = (wv > 0) ? wsum[wv - 1] : 0;
    int sincl = x + waveoff;          // inclusive through this thread's pair
    int excl0 = sincl - s;            // exclusive before v0
    if (g     < N_NODES + 1) offsets[g]     = excl0;
    if (g + 1 < N_NODES + 1) offsets[g + 1] = excl0 + v0;
    if (t == 1023) bsums[blockIdx.x] = sincl;   // block total
}

// ---------------- scan stage B: add block-prefix, init cursors ---------------
__global__ __launch_bounds__(1024) void scanB_k(const int* __restrict__ bsums,
                                                int* __restrict__ offsets,
                                                int* __restrict__ cursor) {
    __shared__ int soff;
    if (threadIdx.x == 0) {
        int a = 0;
        for (int i = 0; i < blockIdx.x; ++i) a += bsums[i];   // <=48 iters
        soff = a;
    }
    __syncthreads();
    const int g = blockIdx.x * SCAN_CH + 2 * threadIdx.x;
#pragma unroll
    for (int k = 0; k < 2; ++k) {
        int gg = g + k;
        if (gg < N_NODES + 1) {
            int o = offsets[gg] + soff;
            offsets[gg] = o;
            if (gg < N_NODES) cursor[gg] = o;
        }
    }
}

// ---------------- scatter edges to final CSR position ------------------------
__global__ __launch_bounds__(256) void scatter_k(const int* __restrict__ erow,
                                                 const int* __restrict__ ecol,
                                                 const float* __restrict__ eval,
                                                 int* __restrict__ cursor,
                                                 unsigned int* __restrict__ cs,
                                                 unsigned short* __restrict__ vs) {
    int i = blockIdx.x * 256 + threadIdx.x;
    const int stride = gridDim.x * 256;
    for (; i < N_EDGES; i += stride) {
        int r = erow[i];
        int pos = atomicAdd(&cursor[r], 1);
        cs[pos] = (unsigned int)ecol[i];
        vs[pos] = f32_to_bf16_rne(eval[i]);
    }
}

// ---------------- segment reduce: out[r] = relu(sum v * xwb[c]) --------------
__global__ __launch_bounds__(256) void aggregate_k(const unsigned short* __restrict__ xwb,
                                                   const int* __restrict__ offsets,
                                                   const unsigned int* __restrict__ cs,
                                                   const unsigned short* __restrict__ vs,
                                                   float* __restrict__ out) {
    const int wave = threadIdx.x >> 6;
    const int lane = threadIdx.x & 63;
    const int r = blockIdx.x * 4 + wave;
    if (r >= N_NODES) return;

    const int start = offsets[r];
    const int end   = offsets[r + 1];
    const int half  = lane >> 5;
    const int hl    = lane & 31;

    float acc[8];
#pragma unroll
    for (int k = 0; k < 8; ++k) acc[k] = 0.f;

#pragma unroll 1
    for (int jb = start; jb < end; jb += 64) {
        int j = jb + lane;
        unsigned int c = 0;
        float v = 0.f;
        if (j < end) {
            c = cs[j];
            v = bf16_bits_to_f32(vs[j]);
        }
        const int cnt = min(64, end - jb);
        const int pairs = (cnt + 1) >> 1;
        const int hp = cnt >> 1;          // # of full (unmasked) pairs
        int t = 0;

#define FMA8(qv, bv)                                                           \
        acc[0] += bv * blo(qv.x); acc[1] += bv * bhi(qv.x);                    \
        acc[2] += bv * blo(qv.y); acc[3] += bv * bhi(qv.y);                    \
        acc[4] += bv * blo(qv.z); acc[5] += bv * bhi(qv.z);                    \
        acc[6] += bv * blo(qv.w); acc[7] += bv * bhi(qv.w);
#define SLOTF(s, qv, bv)                                                       \
        {                                                                      \
            int src = 2 * (t + (s)) + half;                                    \
            unsigned int bc = (unsigned int)__shfl((int)c, src);               \
            bv = __shfl(v, src);                                               \
            qv = ((const uint4*)(xwb + (size_t)bc * D))[hl];                   \
        }

        // ---- 8-deep unmasked fast path (16 edges / iter) ----
#pragma unroll 1
        for (; t + 8 <= hp; t += 8) {
            uint4 q0, q1, q2, q3, q4, q5, q6, q7;
            float b0, b1, b2, b3, b4, b5, b6, b7;
            SLOTF(0, q0, b0) SLOTF(1, q1, b1) SLOTF(2, q2, b2) SLOTF(3, q3, b3)
            SLOTF(4, q4, b4) SLOTF(5, q5, b5) SLOTF(6, q6, b6) SLOTF(7, q7, b7)
            FMA8(q0, b0) FMA8(q1, b1) FMA8(q2, b2) FMA8(q3, b3)
            FMA8(q4, b4) FMA8(q5, b5) FMA8(q6, b6) FMA8(q7, b7)
        }
        // ---- 4-deep unmasked (8 edges) ----
        if (t + 4 <= hp) {
            uint4 q0, q1, q2, q3;
            float b0, b1, b2, b3;
            SLOTF(0, q0, b0) SLOTF(1, q1, b1) SLOTF(2, q2, b2) SLOTF(3, q3, b3)
            FMA8(q0, b0) FMA8(q1, b1) FMA8(q2, b2) FMA8(q3, b3)
            t += 4;
        }
#undef SLOTF

        // ---- masked scalar-pair tail ----
#pragma unroll 1
        for (; t < pairs; ++t) {
            int src = 2 * t + half;
            int srcc = min(src, cnt - 1);
            unsigned int bc = (unsigned int)__shfl((int)c, srcc);
            float bb = __shfl(v, srcc);
            float bv = (src < cnt) ? bb : 0.f;
            uint4 q = ((const uint4*)(xwb + (size_t)bc * D))[hl];
            FMA8(q, bv)
        }
#undef FMA8
    }

    // combine even/odd halves (lane l and l^32 hold the same columns)
#pragma unroll
    for (int k = 0; k < 8; ++k) acc[k] += __shfl_xor(acc[k], 32);

    // redistribute: lane l writes cols 4l..4l+3 (source lane l>>1)
    const int s = lane >> 1;
    const int par = lane & 1;
    float4 o;
    {
        float a0 = __shfl(acc[0], s), b0 = __shfl(acc[4], s);
        float a1 = __shfl(acc[1], s), b1 = __shfl(acc[5], s);
        float a2 = __shfl(acc[2], s), b2 = __shfl(acc[6], s);
        float a3 = __shfl(acc[3], s), b3 = __shfl(acc[7], s);
        o.x = par ? b0 : a0;
        o.y = par ? b1 : a1;
        o.z = par ? b2 : a2;
        o.w = par ? b3 : a3;
    }
    o.x = fmaxf(o.x, 0.f);
    o.y = fmaxf(o.y, 0.f);
    o.z = fmaxf(o.z, 0.f);
    o.w = fmaxf(o.w, 0.f);
    ((float4*)(out + (size_t)r * D))[lane] = o;
}

extern "C" void kernel_launch(void* const* d_in, const int* in_sizes, int n_in,
                              void* d_out, int out_size, void* d_ws, size_t ws_size,
                              hipStream_t stream) {
    const float* x    = (const float*)d_in[0];
    const float* w    = (const float*)d_in[1];
    const int*   erow = (const int*)d_in[2];
    const int*   ecol = (const int*)d_in[3];
    const float* eval = (const float*)d_in[4];
    float* out = (float*)d_out;

    // ---- workspace layout (~72 MB) ----
    char* p = (char*)d_ws;
    auto align = [](size_t v) { return (v + 255) & ~(size_t)255; };

    unsigned short* xwb = (unsigned short*)p;                  // 51.2 MB
    p += align((size_t)N_NODES * D * sizeof(unsigned short));
    unsigned short* wsw = (unsigned short*)p;                  // 128 KiB
    p += align((size_t)D * D * sizeof(unsigned short));
    int* rcnt    = (int*)p;  p += align((size_t)(N_NODES + 1) * sizeof(int));
    int* offsets = (int*)p;  p += align((size_t)(N_NODES + 1) * sizeof(int));
    int* cursor  = (int*)p;  p += align((size_t)N_NODES * sizeof(int));
    int* bsums   = (int*)p;  p += align((size_t)64 * sizeof(int));
    unsigned int*   cs = (unsigned int*)p;    p += align((size_t)N_EDGES * 4);  // 12.8 MB
    unsigned short* vs = (unsigned short*)p;  p += align((size_t)N_EDGES * 2);  // 6.4 MB

    convert_w_k<<<(D * D) / 256, 256, 0, stream>>>(w, wsw);
    gemm_xw_k<<<(N_NODES + 127) / 128, 512, 0, stream>>>(x, wsw, xwb);
    hipMemsetAsync(rcnt, 0, (size_t)(N_NODES + 1) * sizeof(int), stream);
    rhist_k<<<2048, 256, 0, stream>>>(erow, rcnt);
    scanA_k<<<NBLK_S, 1024, 0, stream>>>(rcnt, offsets, bsums);
    scanB_k<<<NBLK_S, 1024, 0, stream>>>(bsums, offsets, cursor);
    scatter_k<<<2048, 256, 0, stream>>>(erow, ecol, eval, cursor, cs, vs);
    aggregate_k<<<(N_NODES + 3) / 4, 256, 0, stream>>>(xwb, offsets, cs, vs, out);
}

// Round 4
// 564.832 us; speedup vs baseline: 1.4391x; 1.4391x over previous
//
#include <hip/hip_runtime.h>
#include <hip/hip_bf16.h>

#define N_NODES 100000
#define N_EDGES 3200000
#define D 256

// ---- coarse buckets: 256 rows each ----
#define RSH2 8
#define RPB2 256
#define NB2 ((N_NODES + RPB2 - 1) / RPB2)          // 391
// ---- fill chunking ----
#define FILL_CH 14336                               // edges per fill block
#define NBLK_F ((N_EDGES + FILL_CH - 1) / FILL_CH)  // 224
#define MAX_BREC 9216                               // LDS-staged recs per bucket (mean 8184, +11sigma)

typedef __attribute__((ext_vector_type(8))) short short8;   // 8 bf16 (4 VGPRs)
typedef __attribute__((ext_vector_type(4))) float floatx4;  // MFMA C/D

__device__ __forceinline__ unsigned short f32_to_bf16_rne(float f) {
    unsigned int u = __float_as_uint(f);
    u += 0x7FFFu + ((u >> 16) & 1u);
    return (unsigned short)(u >> 16);
}
__device__ __forceinline__ float bf16_bits_to_f32(unsigned short b) {
    return __uint_as_float(((unsigned int)b) << 16);
}
__device__ __forceinline__ float blo(unsigned int x) { return __uint_as_float(x << 16); }
__device__ __forceinline__ float bhi(unsigned int x) { return __uint_as_float(x & 0xFFFF0000u); }

// ---------------- W (fp32 [K][N]) -> bf16 MFMA-B-fragment order --------------
__global__ __launch_bounds__(256) void convert_w_k(const float* __restrict__ w,
                                                   unsigned short* __restrict__ wsw) {
    int t = blockIdx.x * 256 + threadIdx.x;
    int j     = t & 7;
    int lane  = (t >> 3) & 63;
    int kstep = (t >> 9) & 7;
    int ntile = t >> 12;
    int k = kstep * 32 + (lane >> 4) * 8 + j;
    int n = ntile * 16 + (lane & 15);
    wsw[t] = f32_to_bf16_rne(w[k * D + n]);
}

// ---------------- xw = x @ W (bf16 MFMA), output bf16 ------------------------
__global__ __launch_bounds__(512) void gemm_xw_k(const float* __restrict__ x,
                                                 const unsigned short* __restrict__ wsw,
                                                 unsigned short* __restrict__ xwb) {
    __shared__ uint4 wlds[8192];  // 128 KiB swizzled bf16 W
    const int tid = threadIdx.x;
#pragma unroll
    for (int i = 0; i < 16; ++i) {
        int idx = i * 512 + tid;
        wlds[idx] = ((const uint4*)wsw)[idx];
    }
    __syncthreads();

    const int lane = tid & 63;
    const int wave = tid >> 6;            // 0..7
    const int q    = lane >> 4;
    const int ml   = lane & 15;
    const long rowBase = (long)blockIdx.x * 128 + wave * 16;
    long arow = rowBase + ml;
    if (arow >= N_NODES) arow = 0;
    const float* xr = x + arow * (long)D;

    floatx4 acc[16];
#pragma unroll
    for (int i = 0; i < 16; ++i) acc[i] = (floatx4){0.f, 0.f, 0.f, 0.f};

    const short8* wfrag = (const short8*)wlds;

#pragma unroll
    for (int ks = 0; ks < 8; ++ks) {
        const float4 a0 = *(const float4*)(xr + ks * 32 + q * 8);
        const float4 a1 = *(const float4*)(xr + ks * 32 + q * 8 + 4);
        short8 af;
        af[0] = (short)f32_to_bf16_rne(a0.x);
        af[1] = (short)f32_to_bf16_rne(a0.y);
        af[2] = (short)f32_to_bf16_rne(a0.z);
        af[3] = (short)f32_to_bf16_rne(a0.w);
        af[4] = (short)f32_to_bf16_rne(a1.x);
        af[5] = (short)f32_to_bf16_rne(a1.y);
        af[6] = (short)f32_to_bf16_rne(a1.z);
        af[7] = (short)f32_to_bf16_rne(a1.w);
#pragma unroll
        for (int nt = 0; nt < 16; ++nt) {
            acc[nt] = __builtin_amdgcn_mfma_f32_16x16x32_bf16(
                af, wfrag[(nt * 8 + ks) * 64 + lane], acc[nt], 0, 0, 0);
        }
    }

#pragma unroll
    for (int nt = 0; nt < 16; ++nt) {
#pragma unroll
        for (int r = 0; r < 4; ++r) {
            long orow = rowBase + q * 4 + r;
            if (orow < N_NODES)
                xwb[orow * (long)D + nt * 16 + ml] = f32_to_bf16_rne(acc[nt][r]);
        }
    }
}

// ---------------- per-(bucket,block) histogram: C[b][blk] --------------------
__global__ __launch_bounds__(256) void hist2_k(const int* __restrict__ erow,
                                               int* __restrict__ C) {
    __shared__ int h[NB2];
    const int tid = threadIdx.x;
    for (int i = tid; i < NB2; i += 256) h[i] = 0;
    __syncthreads();
    const int s = blockIdx.x * FILL_CH;
    const int e = min(s + FILL_CH, N_EDGES);
    for (int i = s + tid; i < e; i += 256) atomicAdd(&h[erow[i] >> RSH2], 1);
    __syncthreads();
    for (int b = tid; b < NB2; b += 256) C[b * NBLK_F + blockIdx.x] = h[b];
}

// ---------------- per-bucket prefix over blocks (in-place), bucket totals ----
__global__ __launch_bounds__(256) void colprefix_k(int* __restrict__ C,
                                                   int* __restrict__ tot) {
    const int wave_id = blockIdx.x * 4 + (threadIdx.x >> 6);
    const int lane = threadIdx.x & 63;
    if (wave_id >= NB2) return;
    int* row = C + wave_id * NBLK_F;
    int run = 0;
#pragma unroll
    for (int ch = 0; ch < NBLK_F; ch += 64) {
        int idx = ch + lane;
        int v = (idx < NBLK_F) ? row[idx] : 0;
        int x = v;
#pragma unroll
        for (int d = 1; d < 64; d <<= 1) {
            int u = __shfl_up(x, d);
            if (lane >= d) x += u;
        }
        int excl = x - v;
        if (idx < NBLK_F) row[idx] = run + excl;
        run += __shfl(x, 63);
    }
    if (lane == 0) tot[wave_id] = run;
}

// ---------------- scan bucket totals -> bucket bases -------------------------
__global__ __launch_bounds__(512) void totscan_k(const int* __restrict__ tot,
                                                 int* __restrict__ bbase) {
    __shared__ int wsum[8];
    const int t = threadIdx.x;
    const int lane = t & 63;
    const int wv = t >> 6;
    int v = (t < NB2) ? tot[t] : 0;
    int x = v;
#pragma unroll
    for (int d = 1; d < 64; d <<= 1) {
        int u = __shfl_up(x, d);
        if (lane >= d) x += u;
    }
    if (lane == 63) wsum[wv] = x;
    __syncthreads();
    if (wv == 0) {
        int y = (lane < 8) ? wsum[lane] : 0;
#pragma unroll
        for (int d = 1; d < 8; d <<= 1) {
            int u = __shfl_up(y, d);
            if (lane >= d) y += u;
        }
        if (lane < 8) wsum[lane] = y;
    }
    __syncthreads();
    int excl = x - v + ((wv > 0) ? wsum[wv - 1] : 0);
    if (t < NB2) bbase[t] = excl;
    if (t == NB2 - 1) bbase[NB2] = excl + v;
}

// ---------------- LDS counting-sort of a chunk into bucket runs --------------
// recs written as coalesced per-(block,bucket) runs (~37 recs = 294 B each);
// zero global atomics (bases precomputed deterministically).
__global__ __launch_bounds__(256) void binfill2_k(const int* __restrict__ erow,
                                                  const int* __restrict__ ecol,
                                                  const float* __restrict__ eval,
                                                  const int* __restrict__ C,
                                                  const int* __restrict__ bbase,
                                                  unsigned long long* __restrict__ recs) {
    __shared__ unsigned long long lrec[FILL_CH];   // 112 KiB
    __shared__ int h[NB2];
    __shared__ int cur[NB2];
    __shared__ int gb[NB2];
    __shared__ int wsum[4];
    const int tid = threadIdx.x;
    const int blk = blockIdx.x;
    const int s = blk * FILL_CH;
    const int e = min(s + FILL_CH, N_EDGES);

    for (int i = tid; i < NB2; i += 256) h[i] = 0;
    __syncthreads();

    // pass A: bucket histogram
    for (int i = s + tid; i < e; i += 256) atomicAdd(&h[erow[i] >> RSH2], 1);
    __syncthreads();

    // scan 391 bins with 256 threads (2 bins/thread, pair-wise)
    {
        const int b0 = 2 * tid, b1 = 2 * tid + 1;
        int v0 = (b0 < NB2) ? h[b0] : 0;
        int v1 = (b1 < NB2) ? h[b1] : 0;
        int sv = v0 + v1;
        const int lane = tid & 63;
        const int wv = tid >> 6;
        int x = sv;
#pragma unroll
        for (int d = 1; d < 64; d <<= 1) {
            int u = __shfl_up(x, d);
            if (lane >= d) x += u;
        }
        if (lane == 63) wsum[wv] = x;
        __syncthreads();
        if (wv == 0) {
            int y = (lane < 4) ? wsum[lane] : 0;
#pragma unroll
            for (int d = 1; d < 4; d <<= 1) {
                int u = __shfl_up(y, d);
                if (lane >= d) y += u;
            }
            if (lane < 4) wsum[lane] = y;
        }
        __syncthreads();
        int excl = x - sv + ((wv > 0) ? wsum[wv - 1] : 0);
        if (b0 < NB2) cur[b0] = excl;
        if (b1 < NB2) cur[b1] = excl + v0;
        // global destination base for this block's run in each bucket
        for (int b = tid; b < NB2; b += 256) gb[b] = bbase[b] + C[b * NBLK_F + blk];
    }
    __syncthreads();

    // pass B: scatter into LDS (bucket-sorted within block)
    for (int i = s + tid; i < e; i += 256) {
        int r = erow[i];
        int b = r >> RSH2;
        unsigned long long rec =
            ((unsigned long long)(r & (RPB2 - 1)) << 33) |
            ((unsigned long long)f32_to_bf16_rne(eval[i]) << 17) |
            (unsigned int)ecol[i];
        int pos = atomicAdd(&cur[b], 1);
        lrec[pos] = rec;
    }
    __syncthreads();

    // flush: one wave per bucket, contiguous run -> contiguous global
    const int lane = tid & 63;
    const int wv = tid >> 6;
    for (int b = wv; b < NB2; b += 4) {
        int len = h[b];
        int start = cur[b] - len;
        int gdst = gb[b];
        for (int o = lane; o < len; o += 64) recs[gdst + o] = lrec[start + o];
    }
}

// ---------------- per-bucket counting sort to full row order -----------------
// stage bucket recs in LDS (74 KiB -> 2 blocks/CU so scatter windows stay
// L2-resident); records beyond MAX_BREC (never in practice, ~11sigma) are
// handled directly from global memory for correctness.
__global__ __launch_bounds__(256) void bsort2_k(const int* __restrict__ bbase,
                                                const unsigned long long* __restrict__ recs,
                                                int* __restrict__ offsets,
                                                unsigned int* __restrict__ cs,
                                                unsigned short* __restrict__ vs) {
    __shared__ unsigned long long lrec[MAX_BREC];  // 73728 B
    __shared__ int hist[RPB2];
    __shared__ int cur[RPB2];
    __shared__ int wsum[4];
    const int t = threadIdx.x;
    const int b = blockIdx.x;
    const int base = bbase[b];
    const int nfull = bbase[b + 1] - base;
    const int n = min(nfull, MAX_BREC);

    for (int i = t; i < n; i += 256) lrec[i] = recs[base + i];
    hist[t] = 0;
    __syncthreads();
    for (int i = t; i < nfull; i += 256) {
        unsigned long long rec = (i < n) ? lrec[i] : recs[base + i];
        atomicAdd(&hist[(int)((rec >> 33) & 255u)], 1);
    }
    __syncthreads();

    // scan 256 bins (1 bin/thread)
    {
        int v = hist[t];
        const int lane = t & 63;
        const int wv = t >> 6;
        int x = v;
#pragma unroll
        for (int d = 1; d < 64; d <<= 1) {
            int u = __shfl_up(x, d);
            if (lane >= d) x += u;
        }
        if (lane == 63) wsum[wv] = x;
        __syncthreads();
        if (wv == 0) {
            int y = (lane < 4) ? wsum[lane] : 0;
#pragma unroll
            for (int d = 1; d < 4; d <<= 1) {
                int u = __shfl_up(y, d);
                if (lane >= d) y += u;
            }
            if (lane < 4) wsum[lane] = y;
        }
        __syncthreads();
        int excl = x - v + ((wv > 0) ? wsum[wv - 1] : 0);
        cur[t] = excl;
        int r = (b << RSH2) + t;
        if (r <= N_NODES) offsets[r] = base + excl;
    }
    __syncthreads();

    for (int i = t; i < nfull; i += 256) {
        unsigned long long rec = (i < n) ? lrec[i] : recs[base + i];
        int rl = (int)((rec >> 33) & 255u);
        int pos = base + atomicAdd(&cur[rl], 1);
        cs[pos] = (unsigned int)(rec & 0x1FFFFu);
        vs[pos] = (unsigned short)((rec >> 17) & 0xFFFFu);
    }
}

// ---------------- segment reduce: out[r] = relu(sum v * xwb[c]) --------------
__global__ __launch_bounds__(256) void aggregate_k(const unsigned short* __restrict__ xwb,
                                                   const int* __restrict__ offsets,
                                                   const unsigned int* __restrict__ cs,
                                                   const unsigned short* __restrict__ vs,
                                                   float* __restrict__ out) {
    const int wave = threadIdx.x >> 6;
    const int lane = threadIdx.x & 63;
    const int r = blockIdx.x * 4 + wave;
    if (r >= N_NODES) return;

    const int start = offsets[r];
    const int end   = offsets[r + 1];
    const int half  = lane >> 5;
    const int hl    = lane & 31;

    float acc[8];
#pragma unroll
    for (int k = 0; k < 8; ++k) acc[k] = 0.f;

#pragma unroll 1
    for (int jb = start; jb < end; jb += 64) {
        int j = jb + lane;
        unsigned int c = 0;
        float v = 0.f;
        if (j < end) {
            c = cs[j];
            v = bf16_bits_to_f32(vs[j]);
        }
        const int cnt = min(64, end - jb);
        const int pairs = (cnt + 1) >> 1;
        const int hp = cnt >> 1;          // # of full (unmasked) pairs
        int t = 0;

#define FMA8(qv, bv)                                                           \
        acc[0] += bv * blo(qv.x); acc[1] += bv * bhi(qv.x);                    \
        acc[2] += bv * blo(qv.y); acc[3] += bv * bhi(qv.y);                    \
        acc[4] += bv * blo(qv.z); acc[5] += bv * bhi(qv.z);                    \
        acc[6] += bv * blo(qv.w); acc[7] += bv * bhi(qv.w);
#define SLOTF(s, qv, bv)                                                       \
        {                                                                      \
            int src = 2 * (t + (s)) + half;                                    \
            unsigned int bc = (unsigned int)__shfl((int)c, src);               \
            bv = __shfl(v, src);                                               \
            qv = ((const uint4*)(xwb + (size_t)bc * D))[hl];                   \
        }

        // ---- 8-deep unmasked fast path (16 edges / iter) ----
#pragma unroll 1
        for (; t + 8 <= hp; t += 8) {
            uint4 q0, q1, q2, q3, q4, q5, q6, q7;
            float b0, b1, b2, b3, b4, b5, b6, b7;
            SLOTF(0, q0, b0) SLOTF(1, q1, b1) SLOTF(2, q2, b2) SLOTF(3, q3, b3)
            SLOTF(4, q4, b4) SLOTF(5, q5, b5) SLOTF(6, q6, b6) SLOTF(7, q7, b7)
            FMA8(q0, b0) FMA8(q1, b1) FMA8(q2, b2) FMA8(q3, b3)
            FMA8(q4, b4) FMA8(q5, b5) FMA8(q6, b6) FMA8(q7, b7)
        }
        // ---- 4-deep unmasked (8 edges) ----
        if (t + 4 <= hp) {
            uint4 q0, q1, q2, q3;
            float b0, b1, b2, b3;
            SLOTF(0, q0, b0) SLOTF(1, q1, b1) SLOTF(2, q2, b2) SLOTF(3, q3, b3)
            FMA8(q0, b0) FMA8(q1, b1) FMA8(q2, b2) FMA8(q3, b3)
            t += 4;
        }
#undef SLOTF

        // ---- masked scalar-pair tail ----
#pragma unroll 1
        for (; t < pairs; ++t) {
            int src = 2 * t + half;
            int srcc = min(src, cnt - 1);
            unsigned int bc = (unsigned int)__shfl((int)c, srcc);
            float bb = __shfl(v, srcc);
            float bv = (src < cnt) ? bb : 0.f;
            uint4 q = ((const uint4*)(xwb + (size_t)bc * D))[hl];
            FMA8(q, bv)
        }
#undef FMA8
    }

    // combine even/odd halves (lane l and l^32 hold the same columns)
#pragma unroll
    for (int k = 0; k < 8; ++k) acc[k] += __shfl_xor(acc[k], 32);

    // redistribute: lane l writes cols 4l..4l+3 (source lane l>>1)
    const int s = lane >> 1;
    const int par = lane & 1;
    float4 o;
    {
        float a0 = __shfl(acc[0], s), b0 = __shfl(acc[4], s);
        float a1 = __shfl(acc[1], s), b1 = __shfl(acc[5], s);
        float a2 = __shfl(acc[2], s), b2 = __shfl(acc[6], s);
        float a3 = __shfl(acc[3], s), b3 = __shfl(acc[7], s);
        o.x = par ? b0 : a0;
        o.y = par ? b1 : a1;
        o.z = par ? b2 : a2;
        o.w = par ? b3 : a3;
    }
    o.x = fmaxf(o.x, 0.f);
    o.y = fmaxf(o.y, 0.f);
    o.z = fmaxf(o.z, 0.f);
    o.w = fmaxf(o.w, 0.f);
    ((float4*)(out + (size_t)r * D))[lane] = o;
}

extern "C" void kernel_launch(void* const* d_in, const int* in_sizes, int n_in,
                              void* d_out, int out_size, void* d_ws, size_t ws_size,
                              hipStream_t stream) {
    const float* x    = (const float*)d_in[0];
    const float* w    = (const float*)d_in[1];
    const int*   erow = (const int*)d_in[2];
    const int*   ecol = (const int*)d_in[3];
    const float* eval = (const float*)d_in[4];
    float* out = (float*)d_out;

    // ---- workspace layout (~97 MB) ----
    char* p = (char*)d_ws;
    auto align = [](size_t v) { return (v + 255) & ~(size_t)255; };

    unsigned short* xwb = (unsigned short*)p;                  // 51.2 MB
    p += align((size_t)N_NODES * D * sizeof(unsigned short));
    unsigned short* wsw = (unsigned short*)p;                  // 128 KiB
    p += align((size_t)D * D * sizeof(unsigned short));
    int* C     = (int*)p;  p += align((size_t)NB2 * NBLK_F * sizeof(int));  // 350 KB
    int* tot   = (int*)p;  p += align((size_t)NB2 * sizeof(int));
    int* bbase = (int*)p;  p += align((size_t)(NB2 + 1) * sizeof(int));
    unsigned long long* recs = (unsigned long long*)p;         // 25.6 MB
    p += align((size_t)N_EDGES * sizeof(unsigned long long));
    unsigned int*   cs = (unsigned int*)p;    p += align((size_t)N_EDGES * 4);  // 12.8 MB
    unsigned short* vs = (unsigned short*)p;  p += align((size_t)N_EDGES * 2);  // 6.4 MB
    int* offsets = (int*)p;  p += align((size_t)(N_NODES + 1) * sizeof(int));   // 400 KB

    convert_w_k<<<(D * D) / 256, 256, 0, stream>>>(w, wsw);
    gemm_xw_k<<<(N_NODES + 127) / 128, 512, 0, stream>>>(x, wsw, xwb);
    hist2_k<<<NBLK_F, 256, 0, stream>>>(erow, C);
    colprefix_k<<<(NB2 + 3) / 4, 256, 0, stream>>>(C, tot);
    totscan_k<<<1, 512, 0, stream>>>(tot, bbase);
    binfill2_k<<<NBLK_F, 256, 0, stream>>>(erow, ecol, eval, C, bbase, recs);
    bsort2_k<<<NB2, 256, 0, stream>>>(bbase, recs, offsets, cs, vs);
    aggregate_k<<<(N_NODES + 3) / 4, 256, 0, stream>>>(xwb, offsets, cs, vs, out);
}

// Round 5
// 545.811 us; speedup vs baseline: 1.4892x; 1.0348x over previous
//
#include <hip/hip_runtime.h>
#include <hip/hip_bf16.h>

#define N_NODES 100000
#define N_EDGES 3200000
#define D 256

// ---- coarse buckets: 64 rows each ----
#define RSH3 6
#define RPB3 64
#define NB3 ((N_NODES + RPB3 - 1) / RPB3)          // 1563
// ---- fill chunking ----
#define FILL_CH 14336                               // edges per fill block
#define NBLK_F ((N_EDGES + FILL_CH - 1) / FILL_CH)  // 224
// ---- fused sort+aggregate LDS caps ----
#define BCAP 2560                                   // mean 2048, +11 sigma
#define OCAP 64                                     // overflow side-buffer

typedef __attribute__((ext_vector_type(8))) short short8;   // 8 bf16 (4 VGPRs)
typedef __attribute__((ext_vector_type(4))) float floatx4;  // MFMA C/D

__device__ __forceinline__ unsigned short f32_to_bf16_rne(float f) {
    unsigned int u = __float_as_uint(f);
    u += 0x7FFFu + ((u >> 16) & 1u);
    return (unsigned short)(u >> 16);
}
__device__ __forceinline__ float bf16_bits_to_f32(unsigned short b) {
    return __uint_as_float(((unsigned int)b) << 16);
}
__device__ __forceinline__ float blo(unsigned int x) { return __uint_as_float(x << 16); }
__device__ __forceinline__ float bhi(unsigned int x) { return __uint_as_float(x & 0xFFFF0000u); }

// ---------------- W (fp32 [K][N]) -> bf16 MFMA-B-fragment order --------------
__global__ __launch_bounds__(256) void convert_w_k(const float* __restrict__ w,
                                                   unsigned short* __restrict__ wsw) {
    int t = blockIdx.x * 256 + threadIdx.x;
    int j     = t & 7;
    int lane  = (t >> 3) & 63;
    int kstep = (t >> 9) & 7;
    int ntile = t >> 12;
    int k = kstep * 32 + (lane >> 4) * 8 + j;
    int n = ntile * 16 + (lane & 15);
    wsw[t] = f32_to_bf16_rne(w[k * D + n]);
}

// ---------------- xw = x @ W (bf16 MFMA), output bf16 ------------------------
__global__ __launch_bounds__(512) void gemm_xw_k(const float* __restrict__ x,
                                                 const unsigned short* __restrict__ wsw,
                                                 unsigned short* __restrict__ xwb) {
    __shared__ uint4 wlds[8192];  // 128 KiB swizzled bf16 W
    const int tid = threadIdx.x;
#pragma unroll
    for (int i = 0; i < 16; ++i) {
        int idx = i * 512 + tid;
        wlds[idx] = ((const uint4*)wsw)[idx];
    }
    __syncthreads();

    const int lane = tid & 63;
    const int wave = tid >> 6;            // 0..7
    const int q    = lane >> 4;
    const int ml   = lane & 15;
    const long rowBase = (long)blockIdx.x * 128 + wave * 16;
    long arow = rowBase + ml;
    if (arow >= N_NODES) arow = 0;
    const float* xr = x + arow * (long)D;

    floatx4 acc[16];
#pragma unroll
    for (int i = 0; i < 16; ++i) acc[i] = (floatx4){0.f, 0.f, 0.f, 0.f};

    const short8* wfrag = (const short8*)wlds;

#pragma unroll
    for (int ks = 0; ks < 8; ++ks) {
        const float4 a0 = *(const float4*)(xr + ks * 32 + q * 8);
        const float4 a1 = *(const float4*)(xr + ks * 32 + q * 8 + 4);
        short8 af;
        af[0] = (short)f32_to_bf16_rne(a0.x);
        af[1] = (short)f32_to_bf16_rne(a0.y);
        af[2] = (short)f32_to_bf16_rne(a0.z);
        af[3] = (short)f32_to_bf16_rne(a0.w);
        af[4] = (short)f32_to_bf16_rne(a1.x);
        af[5] = (short)f32_to_bf16_rne(a1.y);
        af[6] = (short)f32_to_bf16_rne(a1.z);
        af[7] = (short)f32_to_bf16_rne(a1.w);
#pragma unroll
        for (int nt = 0; nt < 16; ++nt) {
            acc[nt] = __builtin_amdgcn_mfma_f32_16x16x32_bf16(
                af, wfrag[(nt * 8 + ks) * 64 + lane], acc[nt], 0, 0, 0);
        }
    }

#pragma unroll
    for (int nt = 0; nt < 16; ++nt) {
#pragma unroll
        for (int r = 0; r < 4; ++r) {
            long orow = rowBase + q * 4 + r;
            if (orow < N_NODES)
                xwb[orow * (long)D + nt * 16 + ml] = f32_to_bf16_rne(acc[nt][r]);
        }
    }
}

// ---------------- per-(bucket,block) histogram: C[b][blk] --------------------
__global__ __launch_bounds__(256) void hist2_k(const int* __restrict__ erow,
                                               int* __restrict__ C) {
    __shared__ int h[NB3];
    const int tid = threadIdx.x;
    for (int i = tid; i < NB3; i += 256) h[i] = 0;
    __syncthreads();
    const int s = blockIdx.x * FILL_CH;
    const int e = min(s + FILL_CH, N_EDGES);
    for (int i = s + tid; i < e; i += 256) atomicAdd(&h[erow[i] >> RSH3], 1);
    __syncthreads();
    for (int b = tid; b < NB3; b += 256) C[b * NBLK_F + blockIdx.x] = h[b];
}

// ---------------- per-bucket prefix over blocks (in-place), bucket totals ----
__global__ __launch_bounds__(256) void colprefix_k(int* __restrict__ C,
                                                   int* __restrict__ tot) {
    const int wave_id = blockIdx.x * 4 + (threadIdx.x >> 6);
    const int lane = threadIdx.x & 63;
    if (wave_id >= NB3) return;
    int* row = C + wave_id * NBLK_F;
    int run = 0;
#pragma unroll
    for (int ch = 0; ch < NBLK_F; ch += 64) {
        int idx = ch + lane;
        int v = (idx < NBLK_F) ? row[idx] : 0;
        int x = v;
#pragma unroll
        for (int d = 1; d < 64; d <<= 1) {
            int u = __shfl_up(x, d);
            if (lane >= d) x += u;
        }
        int excl = x - v;
        if (idx < NBLK_F) row[idx] = run + excl;
        run += __shfl(x, 63);
    }
    if (lane == 0) tot[wave_id] = run;
}

// ---------------- scan bucket totals -> bucket bases -------------------------
__global__ __launch_bounds__(1024) void totscan_k(const int* __restrict__ tot,
                                                  int* __restrict__ bbase) {
    __shared__ int wsum[16];
    const int t = threadIdx.x;
    const int lane = t & 63;
    const int wv = t >> 6;
    const int b0 = 2 * t, b1 = 2 * t + 1;
    int v0 = (b0 < NB3) ? tot[b0] : 0;
    int v1 = (b1 < NB3) ? tot[b1] : 0;
    int sv = v0 + v1;
    int x = sv;
#pragma unroll
    for (int d = 1; d < 64; d <<= 1) {
        int u = __shfl_up(x, d);
        if (lane >= d) x += u;
    }
    if (lane == 63) wsum[wv] = x;
    __syncthreads();
    if (wv == 0) {
        int y = (lane < 16) ? wsum[lane] : 0;
#pragma unroll
        for (int d = 1; d < 16; d <<= 1) {
            int u = __shfl_up(y, d);
            if (lane >= d) y += u;
        }
        if (lane < 16) wsum[lane] = y;
    }
    __syncthreads();
    int excl = x - sv + ((wv > 0) ? wsum[wv - 1] : 0);
    if (b0 < NB3) bbase[b0] = excl;
    if (b1 < NB3) bbase[b1] = excl + v0;
    if (b0 == NB3 - 1) bbase[NB3] = excl + v0;       // NB3 odd: total from v0
    if (b1 == NB3 - 1) bbase[NB3] = excl + v0 + v1;
}

// ---------------- LDS counting-sort of a chunk into bucket runs --------------
// recs written as coalesced per-(block,bucket) runs; zero global atomics.
__global__ __launch_bounds__(512) void binfill3_k(const int* __restrict__ erow,
                                                  const int* __restrict__ ecol,
                                                  const float* __restrict__ eval,
                                                  const int* __restrict__ C,
                                                  const int* __restrict__ bbase,
                                                  unsigned long long* __restrict__ recs) {
    __shared__ unsigned long long lrec[FILL_CH];   // 112 KiB
    __shared__ int h[NB3];
    __shared__ int cur[NB3];
    __shared__ int gb[NB3];
    __shared__ int wsum[8];
    const int tid = threadIdx.x;
    const int blk = blockIdx.x;
    const int s = blk * FILL_CH;
    const int e = min(s + FILL_CH, N_EDGES);

    for (int i = tid; i < NB3; i += 512) h[i] = 0;
    __syncthreads();

    // pass A: bucket histogram
    for (int i = s + tid; i < e; i += 512) atomicAdd(&h[erow[i] >> RSH3], 1);
    __syncthreads();

    // scan NB3 bins with 512 threads (4 bins/thread)
    {
        const int b0 = 4 * tid;
        int v0 = (b0     < NB3) ? h[b0]     : 0;
        int v1 = (b0 + 1 < NB3) ? h[b0 + 1] : 0;
        int v2 = (b0 + 2 < NB3) ? h[b0 + 2] : 0;
        int v3 = (b0 + 3 < NB3) ? h[b0 + 3] : 0;
        int s4 = v0 + v1 + v2 + v3;
        const int lane = tid & 63;
        const int wv = tid >> 6;
        int x = s4;
#pragma unroll
        for (int d = 1; d < 64; d <<= 1) {
            int u = __shfl_up(x, d);
            if (lane >= d) x += u;
        }
        if (lane == 63) wsum[wv] = x;
        __syncthreads();
        if (wv == 0) {
            int y = (lane < 8) ? wsum[lane] : 0;
#pragma unroll
            for (int d = 1; d < 8; d <<= 1) {
                int u = __shfl_up(y, d);
                if (lane >= d) y += u;
            }
            if (lane < 8) wsum[lane] = y;
        }
        __syncthreads();
        int excl = x - s4 + ((wv > 0) ? wsum[wv - 1] : 0);
        if (b0     < NB3) cur[b0]     = excl;
        if (b0 + 1 < NB3) cur[b0 + 1] = excl + v0;
        if (b0 + 2 < NB3) cur[b0 + 2] = excl + v0 + v1;
        if (b0 + 3 < NB3) cur[b0 + 3] = excl + v0 + v1 + v2;
    }
    for (int b = tid; b < NB3; b += 512) gb[b] = bbase[b] + C[b * NBLK_F + blk];
    __syncthreads();

    // pass B: scatter into LDS (bucket-sorted within block)
    for (int i = s + tid; i < e; i += 512) {
        int r = erow[i];
        int b = r >> RSH3;
        unsigned long long rec =
            ((unsigned long long)(r & (RPB3 - 1)) << 33) |
            ((unsigned long long)f32_to_bf16_rne(eval[i]) << 17) |
            (unsigned int)ecol[i];
        int pos = atomicAdd(&cur[b], 1);
        lrec[pos] = rec;
    }
    __syncthreads();

    // flush: one wave per bucket, contiguous run -> contiguous global
    const int lane = tid & 63;
    const int wv = tid >> 6;
    for (int b = wv; b < NB3; b += 8) {
        int len = h[b];
        int start = cur[b] - len;
        int gdst = gb[b];
        for (int o = lane; o < len; o += 64) recs[gdst + o] = lrec[start + o];
    }
}

// ---------------- fused per-bucket sort + segment reduce ---------------------
// one block per 64-row bucket: stage+counting-sort ~2048 recs in LDS, then
// per-wave row gather-reduce (pair-gather), writing relu'd fp32 rows.
// LDS ~21.6 KB -> 7 blocks/CU. Overflow beyond BCAP (+11 sigma) -> ovfl path.
__global__ __launch_bounds__(256) void baggr_k(const unsigned short* __restrict__ xwb,
                                               const int* __restrict__ bbase,
                                               const unsigned long long* __restrict__ recs,
                                               float* __restrict__ out) {
    __shared__ unsigned long long lrec[BCAP];      // 20 KiB
    __shared__ unsigned long long ovfl[OCAP];
    __shared__ int hist[RPB3];
    __shared__ int cur[RPB3];
    __shared__ int novf;
    const int t = threadIdx.x;
    const int b = blockIdx.x;
    const int base = bbase[b];
    const int nfull = bbase[b + 1] - base;

    if (t < RPB3) hist[t] = 0;
    if (t == 0) novf = 0;
    __syncthreads();
    for (int i = t; i < nfull; i += 256)
        atomicAdd(&hist[(int)((recs[base + i] >> 33) & 63u)], 1);
    __syncthreads();

    // exclusive scan of 64 bins (wave 0)
    if (t < 64) {
        int v = hist[t];
        int x = v;
#pragma unroll
        for (int d = 1; d < 64; d <<= 1) {
            int u = __shfl_up(x, d);
            if (t >= d) x += u;
        }
        cur[t] = x - v;
    }
    __syncthreads();

    // scatter into LDS sorted by row_local
    for (int i = t; i < nfull; i += 256) {
        unsigned long long rec = recs[base + i];
        int rl = (int)((rec >> 33) & 63u);
        int pos = atomicAdd(&cur[rl], 1);
        if (pos < BCAP) lrec[pos] = rec;
        else {
            int o = atomicAdd(&novf, 1);
            if (o < OCAP) ovfl[o] = rec;
        }
    }
    __syncthreads();

    const int wave = t >> 6;
    const int lane = t & 63;
    const int half = lane >> 5;
    const int hl   = lane & 31;
    const int nov  = min(novf, OCAP);

#pragma unroll 1
    for (int rr = 0; rr < 16; ++rr) {
        const int rl = wave * 16 + rr;
        const int r = (b << RSH3) + rl;
        if (r >= N_NODES) break;
        const int e_ = cur[rl];
        const int s_ = e_ - hist[rl];
        const int e = min(e_, BCAP);
        const int s = min(s_, BCAP);

        float acc[8];
#pragma unroll
        for (int k = 0; k < 8; ++k) acc[k] = 0.f;

#pragma unroll 1
        for (int jb = s; jb < e; jb += 64) {
            const int cnt = min(64, e - jb);
            const int pairs = (cnt + 1) >> 1;
            const int hp = cnt >> 1;
            int tt = 0;

#define FMA8(qv, bv)                                                           \
            acc[0] += bv * blo(qv.x); acc[1] += bv * bhi(qv.x);                \
            acc[2] += bv * blo(qv.y); acc[3] += bv * bhi(qv.y);                \
            acc[4] += bv * blo(qv.z); acc[5] += bv * bhi(qv.z);                \
            acc[6] += bv * blo(qv.w); acc[7] += bv * bhi(qv.w);
#define SLOTL(ss, qv, bv)                                                      \
            {                                                                  \
                int src = jb + 2 * (tt + (ss)) + half;                         \
                unsigned long long rec = lrec[src];                            \
                unsigned int bc = (unsigned int)(rec & 0x1FFFFu);              \
                bv = bf16_bits_to_f32((unsigned short)((rec >> 17) & 0xFFFFu));\
                qv = ((const uint4*)(xwb + (size_t)bc * D))[hl];               \
            }

            // ---- 8-deep unmasked fast path (16 edges / iter) ----
#pragma unroll 1
            for (; tt + 8 <= hp; tt += 8) {
                uint4 q0, q1, q2, q3, q4, q5, q6, q7;
                float b0, b1, b2, b3, b4, b5, b6, b7;
                SLOTL(0, q0, b0) SLOTL(1, q1, b1) SLOTL(2, q2, b2) SLOTL(3, q3, b3)
                SLOTL(4, q4, b4) SLOTL(5, q5, b5) SLOTL(6, q6, b6) SLOTL(7, q7, b7)
                FMA8(q0, b0) FMA8(q1, b1) FMA8(q2, b2) FMA8(q3, b3)
                FMA8(q4, b4) FMA8(q5, b5) FMA8(q6, b6) FMA8(q7, b7)
            }
            // ---- 4-deep unmasked (8 edges) ----
            if (tt + 4 <= hp) {
                uint4 q0, q1, q2, q3;
                float b0, b1, b2, b3;
                SLOTL(0, q0, b0) SLOTL(1, q1, b1) SLOTL(2, q2, b2) SLOTL(3, q3, b3)
                FMA8(q0, b0) FMA8(q1, b1) FMA8(q2, b2) FMA8(q3, b3)
                tt += 4;
            }
#undef SLOTL
            // ---- masked scalar-pair tail ----
#pragma unroll 1
            for (; tt < pairs; ++tt) {
                int src = jb + 2 * tt + half;
                int srcc = min(src, e - 1);
                unsigned long long rec = lrec[srcc];
                unsigned int bc = (unsigned int)(rec & 0x1FFFFu);
                float vv = bf16_bits_to_f32((unsigned short)((rec >> 17) & 0xFFFFu));
                float bv = (src < e) ? vv : 0.f;
                uint4 q = ((const uint4*)(xwb + (size_t)bc * D))[hl];
                FMA8(q, bv)
            }
        }

        // overflow entries (never in practice): half-0 lanes contribute
#pragma unroll 1
        for (int k = 0; k < nov; ++k) {
            unsigned long long rec = ovfl[k];
            if ((int)((rec >> 33) & 63u) == rl) {
                unsigned int bc = (unsigned int)(rec & 0x1FFFFu);
                float vv = bf16_bits_to_f32((unsigned short)((rec >> 17) & 0xFFFFu));
                float bv = (half == 0) ? vv : 0.f;
                uint4 q = ((const uint4*)(xwb + (size_t)bc * D))[hl];
                FMA8(q, bv)
            }
        }
#undef FMA8

        // combine even/odd halves (lane l and l^32 hold the same columns)
#pragma unroll
        for (int k = 0; k < 8; ++k) acc[k] += __shfl_xor(acc[k], 32);

        // redistribute: lane l writes cols 4l..4l+3 (source lane l>>1)
        const int sl = lane >> 1;
        const int par = lane & 1;
        float4 o;
        {
            float a0 = __shfl(acc[0], sl), c0 = __shfl(acc[4], sl);
            float a1 = __shfl(acc[1], sl), c1 = __shfl(acc[5], sl);
            float a2 = __shfl(acc[2], sl), c2 = __shfl(acc[6], sl);
            float a3 = __shfl(acc[3], sl), c3 = __shfl(acc[7], sl);
            o.x = par ? c0 : a0;
            o.y = par ? c1 : a1;
            o.z = par ? c2 : a2;
            o.w = par ? c3 : a3;
        }
        o.x = fmaxf(o.x, 0.f);
        o.y = fmaxf(o.y, 0.f);
        o.z = fmaxf(o.z, 0.f);
        o.w = fmaxf(o.w, 0.f);
        ((float4*)(out + (size_t)r * D))[lane] = o;
    }
}

extern "C" void kernel_launch(void* const* d_in, const int* in_sizes, int n_in,
                              void* d_out, int out_size, void* d_ws, size_t ws_size,
                              hipStream_t stream) {
    const float* x    = (const float*)d_in[0];
    const float* w    = (const float*)d_in[1];
    const int*   erow = (const int*)d_in[2];
    const int*   ecol = (const int*)d_in[3];
    const float* eval = (const float*)d_in[4];
    float* out = (float*)d_out;

    // ---- workspace layout (~78.5 MB) ----
    char* p = (char*)d_ws;
    auto align = [](size_t v) { return (v + 255) & ~(size_t)255; };

    unsigned short* xwb = (unsigned short*)p;                  // 51.2 MB
    p += align((size_t)N_NODES * D * sizeof(unsigned short));
    unsigned short* wsw = (unsigned short*)p;                  // 128 KiB
    p += align((size_t)D * D * sizeof(unsigned short));
    int* C     = (int*)p;  p += align((size_t)NB3 * NBLK_F * sizeof(int));  // 1.4 MB
    int* tot   = (int*)p;  p += align((size_t)NB3 * sizeof(int));
    int* bbase = (int*)p;  p += align((size_t)(NB3 + 1) * sizeof(int));
    unsigned long long* recs = (unsigned long long*)p;         // 25.6 MB
    p += align((size_t)N_EDGES * sizeof(unsigned long long));

    convert_w_k<<<(D * D) / 256, 256, 0, stream>>>(w, wsw);
    gemm_xw_k<<<(N_NODES + 127) / 128, 512, 0, stream>>>(x, wsw, xwb);
    hist2_k<<<NBLK_F, 256, 0, stream>>>(erow, C);
    colprefix_k<<<(NB3 + 3) / 4, 256, 0, stream>>>(C, tot);
    totscan_k<<<1, 1024, 0, stream>>>(tot, bbase);
    binfill3_k<<<NBLK_F, 512, 0, stream>>>(erow, ecol, eval, C, bbase, recs);
    baggr_k<<<NB3, 256, 0, stream>>>(xwb, bbase, recs, out);
}